// Round 7
// baseline (424.834 us; speedup 1.0000x reference)
//
#include <hip/hip_runtime.h>
#include <hip/hip_bf16.h>

typedef float f32x4 __attribute__((ext_vector_type(4)));
typedef int   i32x4 __attribute__((ext_vector_type(4)));
typedef __bf16 bf16x8 __attribute__((ext_vector_type(8)));
typedef unsigned short u16;
typedef unsigned short u16x4 __attribute__((ext_vector_type(4)));
typedef unsigned short u16x8 __attribute__((ext_vector_type(8)));

#define BM 128
#define BN 128
#define BK 32
#define NT 256
#define MAXE 32

// fp32 -> bf16 native RNE cvt (compiler emits v_cvt_pk_bf16_f32)
__device__ __forceinline__ u16 f2bf(float f) {
  __bf16 h = (__bf16)f;
  return __builtin_bit_cast(u16, h);
}

// inp fp32 -> bf16 pre-pass (~50 MB traffic ~ 10 us)
__global__ __launch_bounds__(256)
void cvt_bf16(const float* __restrict__ in, u16* __restrict__ out, int n8) {
  int i = blockIdx.x * 256 + threadIdx.x;
  if (i < n8) {
    f32x4 a = *(const f32x4*)(in + (long long)i * 8);
    f32x4 b = *(const f32x4*)(in + (long long)i * 8 + 4);
    u16x8 r = { f2bf(a[0]), f2bf(a[1]), f2bf(a[2]), f2bf(a[3]),
                f2bf(b[0]), f2bf(b[1]), f2bf(b[2]), f2bf(b[3]) };
    *(u16x8*)(out + (long long)i * 8) = r;
  }
}

// Grouped GEMM: Out[m,n] = act( sum_k A[m,k]*B[e][n,k] + bias[e][n] )
// A bf16 [T][K], B fp32 [E][N][K], rows grouped by expert.
// r6 post-mortem: NTB along COLUMNS re-fetched B every pass (cold-HBM
// latency > step time for the depth-1 pipeline -> every K-step stalls).
// This version runs NTB along ROWS: one col-tile x NTB consecutive row-tiles
// of the same expert. offB is pass-invariant -> B-slice (0.5 MB) is cold only
// in pass 0, L2/L3-hot after; each w1 byte demanded by exactly one block.
// A changes per pass but A is the small L3-resident activation buffer.
template<bool DO_GELU, bool OUT_BF16, int NTB>
__global__ __launch_bounds__(NT)
void ffn_gemm(const u16* __restrict__ Ain, const float* __restrict__ Bw,
              const float* __restrict__ bias, void* __restrict__ Out,
              const int* __restrict__ counts, int E, int T, int N, int K)
{
  // ---- expert lookup over row-tile GROUPS (NTB tiles per group), batched
  int cs[MAXE];
#pragma unroll
  for (int j = 0; j < MAXE / 4; ++j) {
    if (j * 4 + 3 < E) {
      *(i32x4*)&cs[j * 4] = *(const i32x4*)(counts + j * 4);
    } else {
#pragma unroll
      for (int q = 0; q < 4; ++q) cs[j*4+q] = (j*4+q < E) ? counts[j*4+q] : 0;
    }
  }
  int grp = blockIdx.y, row0e = 0, e = -1, cnt = 0, gi = 0;
#pragma unroll
  for (int i = 0; i < MAXE; ++i) {
    if (i < E && e < 0) {
      int tiles = (cs[i] + BM - 1) / BM;
      int g = (tiles + NTB - 1) / NTB;
      if (grp < g) { e = i; cnt = cs[i]; gi = grp; }
      else { grp -= g; row0e += cs[i]; }
    }
  }
  if (e < 0) return;
  const int tiles_e = (cnt + BM - 1) / BM;
  const int n0 = blockIdx.x * BN;

  const float* Be = Bw + (long long)e * N * K;
  const float* be = bias + (long long)e * N;

  __shared__ u16 As[2][BM][BK];
  __shared__ u16 Bs[2][BN][BK];

  const int t = threadIdx.x;
  const int lane = t & 63;
  const int w = t >> 6, wr = w >> 1, wc = w & 1;  // 2x2 waves -> 64x64 each
  const int NKT = K / BK;

  // pass-invariant B offsets (the whole point of row-NTB)
  long long offB[4];
  int rAri[2], rAci[2];
#pragma unroll
  for (int i = 0; i < 4; ++i) {
    int c = i * NT + t;
    offB[i] = (long long)(n0 + (c >> 3)) * K + ((c & 7) << 2);
  }
#pragma unroll
  for (int i = 0; i < 2; ++i) {
    int c = i * NT + t;
    rAri[i] = c >> 2; rAci[i] = (c & 3) << 3;
  }

  const int rl = lane & 15;
  const int kgf = (lane >> 4) ^ ((rl >> 1) & 3);   // frag-read granule
  const int cl = lane & 15, rg = lane >> 4;

  u16x8 rAu[2]; float rB[16];

  for (int pass = 0; pass < NTB; ++pass) {
    const int tidx = gi * NTB + pass;
    if (tidx >= tiles_e) break;                    // expert-uniform -> safe
    const int row0 = row0e + tidx * BM;
    int valid = cnt - tidx * BM; if (valid > BM) valid = BM;

    long long offA[2];
#pragma unroll
    for (int i = 0; i < 2; ++i) {
      int gr = row0 + rAri[i]; if (gr > T - 1) gr = T - 1;
      offA[i] = (long long)gr * K + rAci[i];
    }

    f32x4 acc[4][4];
#pragma unroll
    for (int i = 0; i < 4; ++i)
#pragma unroll
      for (int j = 0; j < 4; ++j) acc[i][j] = (f32x4){0.f, 0.f, 0.f, 0.f};

    auto load_g = [&](int kt) {
      const int k0 = kt * BK;
#pragma unroll
      for (int i = 0; i < 2; ++i)
        rAu[i] = *(const u16x8*)(Ain + offA[i] + k0);
#pragma unroll
      for (int i = 0; i < 4; ++i) {
        f32x4 v = *(const f32x4*)(Be + offB[i] + k0);
        rB[i*4+0] = v[0]; rB[i*4+1] = v[1]; rB[i*4+2] = v[2]; rB[i*4+3] = v[3];
      }
    };

    // XOR-swizzle on 16B granules: physical granule = kg ^ f(row)
    auto store_tile = [&](int buf) {
#pragma unroll
      for (int i = 0; i < 2; ++i) {
        int c = i * NT + t;
        int row = c >> 2, col = (c & 3) << 3;
        int kg = (col >> 3) ^ ((row >> 1) & 3);
        *(u16x8*)&As[buf][row][kg * 8] = rAu[i];
      }
#pragma unroll
      for (int i = 0; i < 4; ++i) {
        int c = i * NT + t;
        int row = c >> 3, col = (c & 7) << 2;
        int kg = (col >> 3) ^ ((row >> 1) & 3);
        int off = kg * 8 + ((col >> 2) & 1) * 4;
        u16x4 pk = { f2bf(rB[i*4+0]), f2bf(rB[i*4+1]), f2bf(rB[i*4+2]), f2bf(rB[i*4+3]) };
        *(u16x4*)&Bs[buf][row][off] = pk;
      }
    };

    if (NTB > 1 && pass > 0) __syncthreads();  // guard LDS reuse across passes

    load_g(0);
    store_tile(0);
    load_g(1);
    __syncthreads();

    for (int kt = 0; kt < NKT; ++kt) {
      const int cur = kt & 1;

      bf16x8 af[4], bfr[4];
#pragma unroll
      for (int mf = 0; mf < 4; ++mf)
        af[mf] = __builtin_bit_cast(bf16x8, *(const u16x8*)&As[cur][wr*64 + mf*16 + rl][kgf*8]);
#pragma unroll
      for (int nf = 0; nf < 4; ++nf)
        bfr[nf] = __builtin_bit_cast(bf16x8, *(const u16x8*)&Bs[cur][wc*64 + nf*16 + rl][kgf*8]);

      if (kt + 1 < NKT) store_tile(cur ^ 1);
      if (kt + 2 < NKT) load_g(kt + 2);

#pragma unroll
      for (int mf = 0; mf < 4; ++mf)
#pragma unroll
        for (int nf = 0; nf < 4; ++nf)
          acc[mf][nf] = __builtin_amdgcn_mfma_f32_16x16x32_bf16(af[mf], bfr[nf], acc[mf][nf], 0, 0, 0);

      if (kt + 1 < NKT) __syncthreads();
    }

    // epilogue: C/D layout col=lane&15, row=(lane>>4)*4+r [m89/m91]
#pragma unroll
    for (int mf = 0; mf < 4; ++mf) {
#pragma unroll
      for (int nf = 0; nf < 4; ++nf) {
        int gcol = n0 + wc*64 + nf*16 + cl;
        float bv = be[gcol];
#pragma unroll
        for (int r = 0; r < 4; ++r) {
          int lrow = wr*64 + mf*16 + rg*4 + r;
          if (lrow < valid) {
            float v = acc[mf][nf][r] + bv;
            if constexpr (DO_GELU)
              v = 0.5f * v * (1.0f + erff(v * 0.70710678118654752f));
            long long idx = (long long)(row0 + lrow) * N + gcol;
            if constexpr (OUT_BF16) ((u16*)Out)[idx] = f2bf(v);
            else                    ((float*)Out)[idx] = v;
          }
        }
      }
    }
  }
}

extern "C" void kernel_launch(void* const* d_in, const int* in_sizes, int n_in,
                              void* d_out, int out_size, void* d_ws, size_t ws_size,
                              hipStream_t stream) {
  const float* inp = (const float*)d_in[0];
  const float* w1  = (const float*)d_in[1];
  const float* b1  = (const float*)d_in[2];
  const float* w2  = (const float*)d_in[3];
  const float* b2  = (const float*)d_in[4];
  const int* cnts  = (const int*)d_in[5];

  const int E = in_sizes[5];
  const int H = in_sizes[2] / E;       // 4096
  const int D = in_sizes[4] / E;       // 1024
  const int T = in_sizes[0] / D;       // 8192

  u16* hbuf = (u16*)d_ws;                                  // T*H bf16 (64 MB)
  u16* ibuf = (u16*)((char*)d_ws + (size_t)T * H * 2);     // T*D bf16 (16 MB)

  // 0) inp -> bf16
  const int n8 = (T * D) / 8;
  cvt_bf16<<<dim3((n8 + 255) / 256), dim3(256), 0, stream>>>(inp, ibuf, n8);

  // 1) h = gelu(ibuf @ w1^T + b1) — row-NTB=4: grid 32 x (16 + E slack)
  constexpr int NTB1 = 4;
  const int yg1 = (T / BM) / NTB1 + E;
  dim3 g1(H / BN, yg1);
  ffn_gemm<true, true, NTB1><<<g1, dim3(NT), 0, stream>>>(
      ibuf, w1, b1, (void*)hbuf, cnts, E, T, H, D);

  // 2) out = hbuf @ w2^T + b2 — proven config (NTB=1), grid 8 x 80
  const int yg2 = T / BM + E;
  dim3 g2(D / BN, yg2);
  ffn_gemm<false, false, 1><<<g2, dim3(NT), 0, stream>>>(
      hbuf, w2, b2, d_out, cnts, E, T, D, H);
}

// Round 8
// 346.000 us; speedup vs baseline: 1.2278x; 1.2278x over previous
//
#include <hip/hip_runtime.h>
#include <hip/hip_bf16.h>

typedef float f32x4 __attribute__((ext_vector_type(4)));
typedef int   i32x4 __attribute__((ext_vector_type(4)));
typedef __bf16 bf16x8 __attribute__((ext_vector_type(8)));
typedef unsigned short u16;
typedef unsigned short u16x4 __attribute__((ext_vector_type(4)));
typedef unsigned short u16x8 __attribute__((ext_vector_type(8)));

#define BM 128
#define BN 128
#define BK 32
#define NT 256
#define MAXE 32

// fp32 -> bf16 native RNE cvt (compiler emits v_cvt_pk_bf16_f32)
__device__ __forceinline__ u16 f2bf(float f) {
  __bf16 h = (__bf16)f;
  return __builtin_bit_cast(u16, h);
}

// async global->LDS, 16B per lane; LDS dest = wave-uniform base + lane*16.
typedef const __attribute__((address_space(1))) void GAS;
typedef __attribute__((address_space(3))) void LAS;
__device__ __forceinline__ void gl_lds16(const void* g, void* l) {
  __builtin_amdgcn_global_load_lds((GAS*)g, (LAS*)l, 16, 0, 0);
}

// inp fp32 -> bf16 pre-pass (~10 us)
__global__ __launch_bounds__(256)
void cvt_bf16(const float* __restrict__ in, u16* __restrict__ out, int n8) {
  int i = blockIdx.x * 256 + threadIdx.x;
  if (i < n8) {
    f32x4 a = *(const f32x4*)(in + (long long)i * 8);
    f32x4 b = *(const f32x4*)(in + (long long)i * 8 + 4);
    u16x8 r = { f2bf(a[0]), f2bf(a[1]), f2bf(a[2]), f2bf(a[3]),
                f2bf(b[0]), f2bf(b[1]), f2bf(b[2]), f2bf(b[3]) };
    *(u16x8*)(out + (long long)i * 8) = r;
  }
}

// shared expert-prefix lookup: batched loads + predicated register walk
__device__ __forceinline__ int expert_lookup(const int* counts, int E, int bm,
                                             int mt_in, int& row0, int& cnt, int& mt) {
  int cs[MAXE];
#pragma unroll
  for (int j = 0; j < MAXE / 4; ++j) {
    if (j * 4 + 3 < E) *(i32x4*)&cs[j * 4] = *(const i32x4*)(counts + j * 4);
    else {
#pragma unroll
      for (int q = 0; q < 4; ++q) cs[j*4+q] = (j*4+q < E) ? counts[j*4+q] : 0;
    }
  }
  int e = -1; row0 = 0; cnt = 0; mt = mt_in;
#pragma unroll
  for (int i = 0; i < MAXE; ++i) {
    if (i < E && e < 0) {
      int ntl = (cs[i] + bm - 1) / bm;
      if (mt < ntl) { e = i; cnt = cs[i]; }
      else { mt -= ntl; row0 += cs[i]; }
    }
  }
  return e;
}

// ============ GEMM1: 128x128, BK=32, global_load_lds staging ============
// A bf16 [T][K] staged linear; B fp32 [E][N][K] staged with both-sides XOR
// swizzle (rule 21): LDS[r][p] = G[r][p^(r&7)] (16B granules), frag read at
// q^(r&7). fp32->bf16 cvt only on B-frag reads. LDS 48 KB -> 3 blocks/CU.
__global__ __launch_bounds__(NT)
void ffn_gemm1(const u16* __restrict__ Ain, const float* __restrict__ Bw,
               const float* __restrict__ bias, u16* __restrict__ Out,
               const int* __restrict__ counts, int E, int T, int N, int K)
{
  int row0, cnt, mt;
  int e = expert_lookup(counts, E, BM, blockIdx.y, row0, cnt, mt);
  if (e < 0) return;
  int valid = cnt - mt * BM; if (valid > BM) valid = BM;
  row0 += mt * BM;
  const int n0 = blockIdx.x * BN;

  const float* Be = Bw + (long long)e * N * K;
  const float* be = bias + (long long)e * N;

  __shared__ u16  As[2][BM * BK];   // 8 KB per buf (64B rows)
  __shared__ float Bs[2][BN * BK];  // 16 KB per buf (128B rows)

  const int t = threadIdx.x;
  const int lane = t & 63;
  const int w = t >> 6, wr = w >> 1, wc = w & 1;  // 2x2 waves -> 64x64
  const int NKT = K / BK;

  // --- staging descriptors (element offsets sans k0; LDS bases wave-uniform)
  // A: 2 shots x (4 waves x 1KB): rows of 64B; lane -> row=(lane>>2), gran=lane&3
  int aSrc[2], aDst[2];
#pragma unroll
  for (int s = 0; s < 2; ++s) {
    int rb = (s * 4 + w) * 16;
    int r = rb + (lane >> 2);
    int gr = row0 + r; if (gr > T - 1) gr = T - 1;
    aSrc[s] = gr * K + ((lane & 3) << 3);
    aDst[s] = rb * BK;                       // u16 elems, wave-uniform
  }
  // B: 4 shots: rows of 128B; lane -> row=(lane>>3), phys gran p=lane&7,
  // source gran = p ^ (r&7)
  int bSrc[4], bDst[4];
#pragma unroll
  for (int s = 0; s < 4; ++s) {
    int rb = (s * 4 + w) * 8;
    int r = rb + (lane >> 3);
    bSrc[s] = (n0 + r) * K + (((lane & 7) ^ (r & 7)) << 2);
    bDst[s] = rb * BK;                       // float elems, wave-uniform
  }

  auto stage = [&](int buf, int kt) {
    const int k0 = kt * BK;
#pragma unroll
    for (int s = 0; s < 2; ++s) gl_lds16(Ain + aSrc[s] + k0, &As[buf][aDst[s]]);
#pragma unroll
    for (int s = 0; s < 4; ++s) gl_lds16(Be + bSrc[s] + k0, &Bs[buf][bDst[s]]);
  };

  // --- fragment read offsets (K-invariant)
  const int rl = lane & 15, kg = lane >> 4;
  int aoff[4], boff[4];
#pragma unroll
  for (int mf = 0; mf < 4; ++mf) {
    int R = wr * 64 + mf * 16 + rl;
    aoff[mf] = R * BK + kg * 8;              // u16 elems
  }
#pragma unroll
  for (int nf = 0; nf < 4; ++nf) {
    int R = wc * 64 + nf * 16 + rl;
    int go = (2 * kg) ^ (R & 7);             // physical lo granule
    boff[nf] = R * BK + go * 4;              // float elems; hi = boff ^ 4
  }

  f32x4 acc[4][4];
#pragma unroll
  for (int i = 0; i < 4; ++i)
#pragma unroll
    for (int j = 0; j < 4; ++j) acc[i][j] = (f32x4){0.f, 0.f, 0.f, 0.f};

  stage(0, 0);
  __syncthreads();   // vmcnt drained -> tile 0 visible

  for (int kt = 0; kt < NKT; ++kt) {
    const int cur = kt & 1;
    if (kt + 1 < NKT) stage(cur ^ 1, kt + 1);  // in flight across this phase

    bf16x8 af[4], bfr[4];
#pragma unroll
    for (int mf = 0; mf < 4; ++mf)
      af[mf] = __builtin_bit_cast(bf16x8, *(const u16x8*)&As[cur][aoff[mf]]);
#pragma unroll
    for (int nf = 0; nf < 4; ++nf) {
      f32x4 lo = *(const f32x4*)&Bs[cur][boff[nf]];
      f32x4 hi = *(const f32x4*)&Bs[cur][boff[nf] ^ 4];
      u16x8 r = { f2bf(lo[0]), f2bf(lo[1]), f2bf(lo[2]), f2bf(lo[3]),
                  f2bf(hi[0]), f2bf(hi[1]), f2bf(hi[2]), f2bf(hi[3]) };
      bfr[nf] = __builtin_bit_cast(bf16x8, r);
    }

    __builtin_amdgcn_s_setprio(1);
#pragma unroll
    for (int mf = 0; mf < 4; ++mf)
#pragma unroll
      for (int nf = 0; nf < 4; ++nf)
        acc[mf][nf] = __builtin_amdgcn_mfma_f32_16x16x32_bf16(af[mf], bfr[nf], acc[mf][nf], 0, 0, 0);
    __builtin_amdgcn_s_setprio(0);

    __syncthreads();  // drains vmcnt (next tile ready) + lgkm (reads done)
  }

  // epilogue: C/D col=lane&15, row=(lane>>4)*4+r [m89/m91]
  const int cl = lane & 15, rg = lane >> 4;
#pragma unroll
  for (int mf = 0; mf < 4; ++mf) {
#pragma unroll
    for (int nf = 0; nf < 4; ++nf) {
      int gcol = n0 + wc * 64 + nf * 16 + cl;
      float bv = be[gcol];
#pragma unroll
      for (int r = 0; r < 4; ++r) {
        int lrow = wr * 64 + mf * 16 + rg * 4 + r;
        if (lrow < valid) {
          float v = acc[mf][nf][r] + bv;
          v = 0.5f * v * (1.0f + erff(v * 0.70710678118654752f));
          Out[(long long)(row0 + lrow) * N + gcol] = f2bf(v);
        }
      }
    }
  }
}

// ============ GEMM2: r3 reg-staged template (proven ~859 TF) ============
template<bool DO_GELU, bool OUT_BF16>
__global__ __launch_bounds__(NT)
void ffn_gemm(const u16* __restrict__ Ain, const float* __restrict__ Bw,
              const float* __restrict__ bias, void* __restrict__ Out,
              const int* __restrict__ counts, int E, int T, int N, int K)
{
  int row0, cnt, mt;
  int e = expert_lookup(counts, E, BM, blockIdx.y, row0, cnt, mt);
  if (e < 0) return;
  int valid = cnt - mt * BM; if (valid > BM) valid = BM;
  row0 += mt * BM;
  const int n0 = blockIdx.x * BN;

  const float* Be = Bw + (long long)e * N * K;
  const float* be = bias + (long long)e * N;

  __shared__ u16 As[2][BM][BK];
  __shared__ u16 Bs[2][BN][BK];

  const int t = threadIdx.x;
  const int lane = t & 63;
  const int w = t >> 6, wr = w >> 1, wc = w & 1;
  const int NKT = K / BK;

  long long offA[2];
#pragma unroll
  for (int i = 0; i < 2; ++i) {
    int c = i * NT + t;
    int row = c >> 2, col = (c & 3) << 3;
    int gr = row0 + row; if (gr > T - 1) gr = T - 1;
    offA[i] = (long long)gr * K + col;
  }
  long long offB[4];
#pragma unroll
  for (int i = 0; i < 4; ++i) {
    int c = i * NT + t;
    offB[i] = (long long)(n0 + (c >> 3)) * K + ((c & 7) << 2);
  }

  f32x4 acc[4][4];
#pragma unroll
  for (int i = 0; i < 4; ++i)
#pragma unroll
    for (int j = 0; j < 4; ++j) acc[i][j] = (f32x4){0.f, 0.f, 0.f, 0.f};

  u16x8 rAu[2]; float rB[16];

  auto load_g = [&](int kt) {
    const int k0 = kt * BK;
#pragma unroll
    for (int i = 0; i < 2; ++i)
      rAu[i] = *(const u16x8*)(Ain + offA[i] + k0);
#pragma unroll
    for (int i = 0; i < 4; ++i) {
      f32x4 v = *(const f32x4*)(Be + offB[i] + k0);
      rB[i*4+0] = v[0]; rB[i*4+1] = v[1]; rB[i*4+2] = v[2]; rB[i*4+3] = v[3];
    }
  };

  auto store_tile = [&](int buf) {
#pragma unroll
    for (int i = 0; i < 2; ++i) {
      int c = i * NT + t;
      int row = c >> 2, col = (c & 3) << 3;
      int kg2 = (col >> 3) ^ ((row >> 1) & 3);
      *(u16x8*)&As[buf][row][kg2 * 8] = rAu[i];
    }
#pragma unroll
    for (int i = 0; i < 4; ++i) {
      int c = i * NT + t;
      int row = c >> 3, col = (c & 7) << 2;
      int kg2 = (col >> 3) ^ ((row >> 1) & 3);
      int off = kg2 * 8 + ((col >> 2) & 1) * 4;
      u16x4 pk = { f2bf(rB[i*4+0]), f2bf(rB[i*4+1]), f2bf(rB[i*4+2]), f2bf(rB[i*4+3]) };
      *(u16x4*)&Bs[buf][row][off] = pk;
    }
  };

  load_g(0);
  store_tile(0);
  load_g(1);
  __syncthreads();

  const int rl = lane & 15;
  const int kgf = (lane >> 4) ^ ((rl >> 1) & 3);

  for (int kt = 0; kt < NKT; ++kt) {
    const int cur = kt & 1;

    bf16x8 af[4], bfr[4];
#pragma unroll
    for (int mf = 0; mf < 4; ++mf)
      af[mf] = __builtin_bit_cast(bf16x8, *(const u16x8*)&As[cur][wr*64 + mf*16 + rl][kgf*8]);
#pragma unroll
    for (int nf = 0; nf < 4; ++nf)
      bfr[nf] = __builtin_bit_cast(bf16x8, *(const u16x8*)&Bs[cur][wc*64 + nf*16 + rl][kgf*8]);

    if (kt + 1 < NKT) store_tile(cur ^ 1);
    if (kt + 2 < NKT) load_g(kt + 2);

#pragma unroll
    for (int mf = 0; mf < 4; ++mf)
#pragma unroll
      for (int nf = 0; nf < 4; ++nf)
        acc[mf][nf] = __builtin_amdgcn_mfma_f32_16x16x32_bf16(af[mf], bfr[nf], acc[mf][nf], 0, 0, 0);

    if (kt + 1 < NKT) __syncthreads();
  }

  const int cl = lane & 15, rg = lane >> 4;
#pragma unroll
  for (int mf = 0; mf < 4; ++mf) {
#pragma unroll
    for (int nf = 0; nf < 4; ++nf) {
      int gcol = n0 + wc*64 + nf*16 + cl;
      float bv = be[gcol];
#pragma unroll
      for (int r = 0; r < 4; ++r) {
        int lrow = wr*64 + mf*16 + rg*4 + r;
        if (lrow < valid) {
          float v = acc[mf][nf][r] + bv;
          if constexpr (DO_GELU)
            v = 0.5f * v * (1.0f + erff(v * 0.70710678118654752f));
          long long idx = (long long)(row0 + lrow) * N + gcol;
          if constexpr (OUT_BF16) ((u16*)Out)[idx] = f2bf(v);
          else                    ((float*)Out)[idx] = v;
        }
      }
    }
  }
}

extern "C" void kernel_launch(void* const* d_in, const int* in_sizes, int n_in,
                              void* d_out, int out_size, void* d_ws, size_t ws_size,
                              hipStream_t stream) {
  const float* inp = (const float*)d_in[0];
  const float* w1  = (const float*)d_in[1];
  const float* b1  = (const float*)d_in[2];
  const float* w2  = (const float*)d_in[3];
  const float* b2  = (const float*)d_in[4];
  const int* cnts  = (const int*)d_in[5];

  const int E = in_sizes[5];
  const int H = in_sizes[2] / E;       // 4096
  const int D = in_sizes[4] / E;       // 1024
  const int T = in_sizes[0] / D;       // 8192

  u16* hbuf = (u16*)d_ws;                                  // T*H bf16 (64 MB)
  u16* ibuf = (u16*)((char*)d_ws + (size_t)T * H * 2);     // T*D bf16 (16 MB)

  // 0) inp -> bf16
  const int n8 = (T * D) / 8;
  cvt_bf16<<<dim3((n8 + 255) / 256), dim3(256), 0, stream>>>(inp, ibuf, n8);

  const int tiles = T / BM + E;  // upper bound on row-tiles

  // 1) h = gelu(ibuf @ w1^T + b1) — gload_lds staging, grid 32 x 80
  dim3 g1(H / BN, tiles);
  ffn_gemm1<<<g1, dim3(NT), 0, stream>>>(ibuf, w1, b1, hbuf, cnts, E, T, H, D);

  // 2) out = hbuf @ w2^T + b2 — proven r3 template, grid 8 x 80
  dim3 g2(D / BN, tiles);
  ffn_gemm<false, false><<<g2, dim3(NT), 0, stream>>>(
      hbuf, w2, b2, d_out, cnts, E, T, D, H);
}